// Round 8
// baseline (842.890 us; speedup 1.0000x reference)
//
#include <hip/hip_runtime.h>

#define K_CODES 8192
#define D_DIM   512
#define N_ROWS  16384
#define NSPLIT  32          /* code splits of 256 */
#define CAP     8
#define T2      2.0e-4f     /* dot-space margin (validated r4-r7) */

typedef __attribute__((ext_vector_type(8))) short bf16x8;
typedef __attribute__((ext_vector_type(4))) float f32x4;
typedef unsigned char uchar;
typedef unsigned short ushort;
typedef unsigned long long u64;

// raw barrier: waits LDS ops only, leaves global-load vmcnt in flight
#define BAR_LDS() asm volatile("s_waitcnt lgkmcnt(0)\n\ts_barrier" ::: "memory")

__device__ __forceinline__ unsigned fkey(float f) {
    unsigned b = __float_as_uint(f);
    return (b & 0x80000000u) ? ~b : (b | 0x80000000u);
}
__device__ __forceinline__ float finv(unsigned k) {
    return __uint_as_float((k & 0x80000000u) ? (k & 0x7fffffffu) : ~k);
}

__device__ __forceinline__ unsigned pk_bf16(float a, float b) {
    unsigned ua = __float_as_uint(a), ub = __float_as_uint(b);
    ua = (ua + 0x7fffu + ((ua >> 16) & 1u)) >> 16;
    ub = (ub + 0x7fffu + ((ub >> 16) & 1u)) & 0xffff0000u;
    return ua | ub;
}

// ---------------------------------------------------------------------------
// K0 (pre path): bf16 conversion of x/cb + exact ||z||^2 (numpy pairwise
// bit-exact, 32-lane parallel) + done-counter init.
// ---------------------------------------------------------------------------
__global__ void vq_prepass(const float* __restrict__ x, const float* __restrict__ cb,
                           unsigned* __restrict__ xb, unsigned* __restrict__ cbb,
                           float* __restrict__ sn, int* __restrict__ done) {
    const int bid = blockIdx.x;
    const int t = threadIdx.x;
    if (bid < 6144) {
        const size_t gid = (size_t)bid * 256 + t;
        const size_t nx = (size_t)N_ROWS * D_DIM / 8;     // 1048576
        if (gid < nx) {
            const float4 f0 = ((const float4*)x)[gid * 2];
            const float4 f1 = ((const float4*)x)[gid * 2 + 1];
            ((uint4*)xb)[gid] = make_uint4(pk_bf16(f0.x, f0.y), pk_bf16(f0.z, f0.w),
                                           pk_bf16(f1.x, f1.y), pk_bf16(f1.z, f1.w));
        } else {
            const size_t g = gid - nx;
            const float4 f0 = ((const float4*)cb)[g * 2];
            const float4 f1 = ((const float4*)cb)[g * 2 + 1];
            ((uint4*)cbb)[g] = make_uint4(pk_bf16(f0.x, f0.y), pk_bf16(f0.z, f0.w),
                                          pk_bf16(f1.x, f1.y), pk_bf16(f1.z, f1.w));
        }
    } else {
        const int base = (bid - 6144) * 8;
        if (bid == 6144 && t == 0) *done = 0;
        const int wave = t >> 6, lane = t & 63;
        const int row = base + wave * 2 + (lane >> 5);
        const int l = lane & 31, b = l >> 3, j = l & 7;
        const float* a = x + (size_t)row * D_DIM + b * 128 + j;
        float r = __fmul_rn(a[0], a[0]);
#pragma unroll
        for (int i = 1; i < 16; ++i) {
            const float v = a[i * 8];
            r = __fadd_rn(r, __fmul_rn(v, v));
        }
        r = __fadd_rn(r, __shfl_xor(r, 1));
        r = __fadd_rn(r, __shfl_xor(r, 2));
        r = __fadd_rn(r, __shfl_xor(r, 4));
        r = __fadd_rn(r, __shfl_xor(r, 8));
        r = __fadd_rn(r, __shfl_xor(r, 16));
        if (l == 0) sn[row] = r;
    }
}

// non-pre path: standalone sn + done init
__global__ __launch_bounds__(256)
void vq_sn(const float* __restrict__ x, float* __restrict__ sn,
           int* __restrict__ done) {
    const int t = threadIdx.x;
    const int base = blockIdx.x * 8;
    if (blockIdx.x == 0 && t == 0) *done = 0;
    const int wave = t >> 6, lane = t & 63;
    const int row = base + wave * 2 + (lane >> 5);
    const int l = lane & 31, b = l >> 3, j = l & 7;
    const float* a = x + (size_t)row * D_DIM + b * 128 + j;
    float r = __fmul_rn(a[0], a[0]);
#pragma unroll
    for (int i = 1; i < 16; ++i) {
        const float v = a[i * 8];
        r = __fadd_rn(r, __fmul_rn(v, v));
    }
    r = __fadd_rn(r, __shfl_xor(r, 1));
    r = __fadd_rn(r, __shfl_xor(r, 2));
    r = __fadd_rn(r, __shfl_xor(r, 4));
    r = __fadd_rn(r, __shfl_xor(r, 8));
    r = __fadd_rn(r, __shfl_xor(r, 16));
    if (l == 0) sn[row] = r;
}

// ---------------------------------------------------------------------------
// K1 (pre): screening GEMM, double-buffered LDS, ONE raw barrier per K-slab
// (lgkm-only wait: prefetch loads stay in flight across the barrier).
// 128 rows x 256 codes, 4 waves of 64x128, bf16-hi MFMA, XOR-swizzled LDS.
// ---------------------------------------------------------------------------
__global__ __launch_bounds__(256, 2)
void vq_screen_pre(const ushort* __restrict__ xb, const ushort* __restrict__ cbb,
                   float* __restrict__ g_dmax, uchar* __restrict__ g_cnt,
                   uchar* __restrict__ g_cand) {
    __shared__ ushort Ash[2][128 * 32];   // 2 x 8 KB
    __shared__ ushort Bsh[2][256 * 32];   // 2 x 16 KB
    __shared__ unsigned vkey[128];
    __shared__ int ccnt[128];
    __shared__ uchar clist[128][CAP];

    const int t    = threadIdx.x;
    const int w    = t >> 6, lane = t & 63;
    const int fr   = lane & 15;
    const int quad = lane >> 4;
    const int wr   = (w & 1) * 64;
    const int wc   = (w >> 1) * 128;
    const int row0  = blockIdx.y * 128;
    const int kbase = blockIdx.x * 256;

    if (t < 128) { vkey[t] = 0u; ccnt[t] = 0; }

    // staging write offsets (XOR swizzle, within one buffer)
    const int r = t >> 1, h = t & 1;
    const int sA = (r >> 1) & 3;
    const int ca0 = (2 * h) ^ sA;
    const int aw0 = r * 32 + ca0 * 8;
    const int aw1 = r * 32 + (ca0 ^ 1) * 8;
    const int sB = (t >> 1) & 3;
    const int bw0 = t * 32 + (0 ^ sB) * 8;
    const int bw1 = t * 32 + (1 ^ sB) * 8;
    const int bw2 = t * 32 + (2 ^ sB) * 8;
    const int bw3 = t * 32 + (3 ^ sB) * 8;

    // frag read offsets
    int aoff[4], boff[8];
#pragma unroll
    for (int i = 0; i < 4; ++i) {
        const int rw = wr + i * 16 + fr;
        aoff[i] = rw * 32 + ((quad ^ (rw >> 1)) & 3) * 8;
    }
#pragma unroll
    for (int j = 0; j < 8; ++j) {
        const int rw = wc + j * 16 + fr;
        boff[j] = rw * 32 + ((quad ^ (rw >> 1)) & 3) * 8;
    }

    const char* gA = (const char*)(xb  + (size_t)(row0 + r) * D_DIM + h * 16);
    const char* gB = (const char*)(cbb + (size_t)(kbase + t) * D_DIM);

    f32x4 acc[4][8];
#pragma unroll
    for (int i = 0; i < 4; ++i)
#pragma unroll
        for (int j = 0; j < 8; ++j) acc[i][j] = (f32x4)0.0f;

    // prime: slab 0 -> buf0, prefetch slab 1 into regs
    uint4 a0 = *(const uint4*)(gA);
    uint4 a1 = *(const uint4*)(gA + 16);
    uint4 b0 = *(const uint4*)(gB);
    uint4 b1 = *(const uint4*)(gB + 16);
    uint4 b2 = *(const uint4*)(gB + 32);
    uint4 b3 = *(const uint4*)(gB + 48);
    *(uint4*)&Ash[0][aw0] = a0; *(uint4*)&Ash[0][aw1] = a1;
    *(uint4*)&Bsh[0][bw0] = b0; *(uint4*)&Bsh[0][bw1] = b1;
    *(uint4*)&Bsh[0][bw2] = b2; *(uint4*)&Bsh[0][bw3] = b3;
    a0 = *(const uint4*)(gA + 64);
    a1 = *(const uint4*)(gA + 64 + 16);
    b0 = *(const uint4*)(gB + 64);
    b1 = *(const uint4*)(gB + 64 + 16);
    b2 = *(const uint4*)(gB + 64 + 32);
    b3 = *(const uint4*)(gB + 64 + 48);
    BAR_LDS();

    for (int dc = 0; dc < 16; ++dc) {
        const int p = dc & 1;
        bf16x8 af[4], bfv[8];
#pragma unroll
        for (int i = 0; i < 4; ++i) af[i] = *(const bf16x8*)&Ash[p][aoff[i]];
#pragma unroll
        for (int j = 0; j < 8; ++j) bfv[j] = *(const bf16x8*)&Bsh[p][boff[j]];
        // write prefetched slab dc+1 into the other buffer (its readers
        // finished at the previous barrier)
        *(uint4*)&Ash[p ^ 1][aw0] = a0; *(uint4*)&Ash[p ^ 1][aw1] = a1;
        *(uint4*)&Bsh[p ^ 1][bw0] = b0; *(uint4*)&Bsh[p ^ 1][bw1] = b1;
        *(uint4*)&Bsh[p ^ 1][bw2] = b2; *(uint4*)&Bsh[p ^ 1][bw3] = b3;
        // issue prefetch of slab dc+2 (wraps harmlessly at the end)
        const int dn = (dc + 2) & 15;
        a0 = *(const uint4*)(gA + dn * 64);
        a1 = *(const uint4*)(gA + dn * 64 + 16);
        b0 = *(const uint4*)(gB + dn * 64);
        b1 = *(const uint4*)(gB + dn * 64 + 16);
        b2 = *(const uint4*)(gB + dn * 64 + 32);
        b3 = *(const uint4*)(gB + dn * 64 + 48);
#pragma unroll
        for (int i = 0; i < 4; ++i)
#pragma unroll
            for (int j = 0; j < 8; ++j)
                acc[i][j] = __builtin_amdgcn_mfma_f32_16x16x32_bf16(af[i], bfv[j], acc[i][j], 0, 0, 0);
        BAR_LDS();
    }

    // epilogue: per-row split max, then candidate push (validated r5-r7)
#pragma unroll
    for (int i = 0; i < 4; ++i)
#pragma unroll
        for (int rg = 0; rg < 4; ++rg) {
            float m = acc[i][0][rg];
#pragma unroll
            for (int j = 1; j < 8; ++j) m = fmaxf(m, acc[i][j][rg]);
            m = fmaxf(m, __shfl_xor(m, 1));
            m = fmaxf(m, __shfl_xor(m, 2));
            m = fmaxf(m, __shfl_xor(m, 4));
            m = fmaxf(m, __shfl_xor(m, 8));
            if (fr == 0) atomicMax(&vkey[wr + i * 16 + quad * 4 + rg], fkey(m));
        }
    __syncthreads();
#pragma unroll
    for (int i = 0; i < 4; ++i)
#pragma unroll
        for (int rg = 0; rg < 4; ++rg) {
            const int row = wr + i * 16 + quad * 4 + rg;
            const float thr = finv(vkey[row]) - T2;
#pragma unroll
            for (int j = 0; j < 8; ++j) {
                if (acc[i][j][rg] >= thr) {
                    int p = atomicAdd(&ccnt[row], 1);
                    if (p < CAP) clist[row][p] = (uchar)(wc + j * 16 + fr);
                }
            }
        }
    __syncthreads();
    if (t < 128) {
        const size_t o = (size_t)(row0 + t) * NSPLIT + blockIdx.x;
        g_dmax[o] = finv(vkey[t]);
        int c = ccnt[t];
        g_cnt[o] = (uchar)(c > 255 ? 255 : c);
        ((uint2*)g_cand)[o] = *(const uint2*)clist[t];
    }
}

// ---------------------------------------------------------------------------
// K1 (non-pre fallback): r7-validated two-barrier screen with in-kernel
// bf16 conversion.
// ---------------------------------------------------------------------------
__global__ __launch_bounds__(256, 2)
void vq_screen_np(const float* __restrict__ x, const float* __restrict__ cb,
                  float* __restrict__ g_dmax, uchar* __restrict__ g_cnt,
                  uchar* __restrict__ g_cand) {
    __shared__ ushort Ash[128 * 32];
    __shared__ ushort Bsh[256 * 32];
    __shared__ unsigned vkey[128];
    __shared__ int ccnt[128];
    __shared__ uchar clist[128][CAP];

    const int t    = threadIdx.x;
    const int w    = t >> 6, lane = t & 63;
    const int fr   = lane & 15;
    const int quad = lane >> 4;
    const int wr   = (w & 1) * 64;
    const int wc   = (w >> 1) * 128;
    const int row0  = blockIdx.y * 128;
    const int kbase = blockIdx.x * 256;

    if (t < 128) { vkey[t] = 0u; ccnt[t] = 0; }

    const int r = t >> 1, h = t & 1;
    const int sA = (r >> 1) & 3;
    const int ca0 = (2 * h) ^ sA;
    ushort* awp0 = &Ash[r * 32 + ca0 * 8];
    ushort* awp1 = &Ash[r * 32 + (ca0 ^ 1) * 8];
    const int sB = (t >> 1) & 3;
    ushort* bwp0 = &Bsh[t * 32 + (0 ^ sB) * 8];
    ushort* bwp1 = &Bsh[t * 32 + (1 ^ sB) * 8];
    ushort* bwp2 = &Bsh[t * 32 + (2 ^ sB) * 8];
    ushort* bwp3 = &Bsh[t * 32 + (3 ^ sB) * 8];

    int aoff[4], boff[8];
#pragma unroll
    for (int i = 0; i < 4; ++i) {
        const int rw = wr + i * 16 + fr;
        aoff[i] = rw * 32 + ((quad ^ (rw >> 1)) & 3) * 8;
    }
#pragma unroll
    for (int j = 0; j < 8; ++j) {
        const int rw = wc + j * 16 + fr;
        boff[j] = rw * 32 + ((quad ^ (rw >> 1)) & 3) * 8;
    }

    f32x4 acc[4][8];
#pragma unroll
    for (int i = 0; i < 4; ++i)
#pragma unroll
        for (int j = 0; j < 8; ++j) acc[i][j] = (f32x4)0.0f;

    const char* gA = (const char*)(x  + (size_t)(row0 + r) * D_DIM + h * 16);
    const char* gB = (const char*)(cb + (size_t)(kbase + t) * D_DIM);
    for (int dc = 0; dc < 16; ++dc) {
        const float4* fa = (const float4*)(gA + dc * 128);
        float4 f0 = fa[0], f1 = fa[1], f2 = fa[2], f3 = fa[3];
        uint4 a0 = make_uint4(pk_bf16(f0.x, f0.y), pk_bf16(f0.z, f0.w),
                              pk_bf16(f1.x, f1.y), pk_bf16(f1.z, f1.w));
        uint4 a1 = make_uint4(pk_bf16(f2.x, f2.y), pk_bf16(f2.z, f2.w),
                              pk_bf16(f3.x, f3.y), pk_bf16(f3.z, f3.w));
        const float4* fb = (const float4*)(gB + dc * 128);
        float4 g0 = fb[0], g1 = fb[1], g2 = fb[2], g3 = fb[3];
        float4 g4 = fb[4], g5 = fb[5], g6 = fb[6], g7 = fb[7];
        uint4 b0 = make_uint4(pk_bf16(g0.x, g0.y), pk_bf16(g0.z, g0.w),
                              pk_bf16(g1.x, g1.y), pk_bf16(g1.z, g1.w));
        uint4 b1 = make_uint4(pk_bf16(g2.x, g2.y), pk_bf16(g2.z, g2.w),
                              pk_bf16(g3.x, g3.y), pk_bf16(g3.z, g3.w));
        uint4 b2 = make_uint4(pk_bf16(g4.x, g4.y), pk_bf16(g4.z, g4.w),
                              pk_bf16(g5.x, g5.y), pk_bf16(g5.z, g5.w));
        uint4 b3 = make_uint4(pk_bf16(g6.x, g6.y), pk_bf16(g6.z, g6.w),
                              pk_bf16(g7.x, g7.y), pk_bf16(g7.z, g7.w));
        __syncthreads();
        *(uint4*)awp0 = a0; *(uint4*)awp1 = a1;
        *(uint4*)bwp0 = b0; *(uint4*)bwp1 = b1;
        *(uint4*)bwp2 = b2; *(uint4*)bwp3 = b3;
        __syncthreads();
        bf16x8 af[4], bfv[8];
#pragma unroll
        for (int i = 0; i < 4; ++i) af[i] = *(const bf16x8*)&Ash[aoff[i]];
#pragma unroll
        for (int j = 0; j < 8; ++j) bfv[j] = *(const bf16x8*)&Bsh[boff[j]];
#pragma unroll
        for (int i = 0; i < 4; ++i)
#pragma unroll
            for (int j = 0; j < 8; ++j)
                acc[i][j] = __builtin_amdgcn_mfma_f32_16x16x32_bf16(af[i], bfv[j], acc[i][j], 0, 0, 0);
    }

    __syncthreads();
#pragma unroll
    for (int i = 0; i < 4; ++i)
#pragma unroll
        for (int rg = 0; rg < 4; ++rg) {
            float m = acc[i][0][rg];
#pragma unroll
            for (int j = 1; j < 8; ++j) m = fmaxf(m, acc[i][j][rg]);
            m = fmaxf(m, __shfl_xor(m, 1));
            m = fmaxf(m, __shfl_xor(m, 2));
            m = fmaxf(m, __shfl_xor(m, 4));
            m = fmaxf(m, __shfl_xor(m, 8));
            if (fr == 0) atomicMax(&vkey[wr + i * 16 + quad * 4 + rg], fkey(m));
        }
    __syncthreads();
#pragma unroll
    for (int i = 0; i < 4; ++i)
#pragma unroll
        for (int rg = 0; rg < 4; ++rg) {
            const int row = wr + i * 16 + quad * 4 + rg;
            const float thr = finv(vkey[row]) - T2;
#pragma unroll
            for (int j = 0; j < 8; ++j) {
                if (acc[i][j][rg] >= thr) {
                    int p = atomicAdd(&ccnt[row], 1);
                    if (p < CAP) clist[row][p] = (uchar)(wc + j * 16 + fr);
                }
            }
        }
    __syncthreads();
    if (t < 128) {
        const size_t o = (size_t)(row0 + t) * NSPLIT + blockIdx.x;
        g_dmax[o] = finv(vkey[t]);
        int c = ccnt[t];
        g_cnt[o] = (uchar)(c > 255 ? 255 : c);
        ((uint2*)g_cand)[o] = *(const uint2*)clist[t];
    }
}

// bit-exact numpy fp32 (baseline SSE3) einsum — validated absmax=0 (r2,r4-r7)
__device__ __forceinline__ float np_einsum_dot(const float* __restrict__ a,
                                               const float* __restrict__ b) {
    float S0 = 0.f, S1 = 0.f, S2 = 0.f, S3 = 0.f;
    for (int i = 0; i < D_DIM; i += 16) {
        S0 = __fadd_rn(S0, __fmul_rn(a[i + 12], b[i + 12]));
        S1 = __fadd_rn(S1, __fmul_rn(a[i + 13], b[i + 13]));
        S2 = __fadd_rn(S2, __fmul_rn(a[i + 14], b[i + 14]));
        S3 = __fadd_rn(S3, __fmul_rn(a[i + 15], b[i + 15]));
        S0 = __fadd_rn(S0, __fmul_rn(a[i +  8], b[i +  8]));
        S1 = __fadd_rn(S1, __fmul_rn(a[i +  9], b[i +  9]));
        S2 = __fadd_rn(S2, __fmul_rn(a[i + 10], b[i + 10]));
        S3 = __fadd_rn(S3, __fmul_rn(a[i + 11], b[i + 11]));
        S0 = __fadd_rn(S0, __fmul_rn(a[i +  4], b[i +  4]));
        S1 = __fadd_rn(S1, __fmul_rn(a[i +  5], b[i +  5]));
        S2 = __fadd_rn(S2, __fmul_rn(a[i +  6], b[i +  6]));
        S3 = __fadd_rn(S3, __fmul_rn(a[i +  7], b[i +  7]));
        S0 = __fadd_rn(S0, __fmul_rn(a[i +  0], b[i +  0]));
        S1 = __fadd_rn(S1, __fmul_rn(a[i +  1], b[i +  1]));
        S2 = __fadd_rn(S2, __fmul_rn(a[i +  2], b[i +  2]));
        S3 = __fadd_rn(S3, __fmul_rn(a[i +  3], b[i +  3]));
    }
    return __fadd_rn(__fadd_rn(S0, S1), __fadd_rn(S2, S3));
}

// ---------------------------------------------------------------------------
// K2: fused tail — block per row (128 threads): split-maxima scan, exact
// replay (packed-u64 min = first-index tie semantics), gather/ST/loss, and
// last-block-done loss finalize.
// ---------------------------------------------------------------------------
__global__ __launch_bounds__(128)
void vq_tail(const float* __restrict__ x, const float* __restrict__ cb,
             const float* __restrict__ sn_arr, const float* __restrict__ g_dmax,
             const uchar* __restrict__ g_cnt, const uchar* __restrict__ g_cand,
             float* __restrict__ idx_f, float* __restrict__ zq,
             double* __restrict__ psum, int* __restrict__ done,
             float* __restrict__ losses) {
    const int row = blockIdx.x;
    const int t = threadIdx.x, lane = t & 63, wv = t >> 6;
    __shared__ u64 s_red[2];
    __shared__ double s_ls[2];
    __shared__ int s_last;

    const float* dm = g_dmax + (size_t)row * NSPLIT;
    float g = dm[lane & 31];
    g = fmaxf(g, __shfl_xor(g, 1));
    g = fmaxf(g, __shfl_xor(g, 2));
    g = fmaxf(g, __shfl_xor(g, 4));
    g = fmaxf(g, __shfl_xor(g, 8));
    g = fmaxf(g, __shfl_xor(g, 16));
    const float thr = g - T2;

    // per-lane split stats (lanes 0..31 own one split each)
    int contr = 0;
    unsigned firstkey = 0xffffffffu;
    if (lane < 32) {
        if (dm[lane] >= thr) {
            const size_t o = (size_t)row * NSPLIT + lane;
            const int c = g_cnt[o];
            contr = (c > CAP) ? 256 : c;
            firstkey = ((unsigned)lane << 16) | (unsigned)(lane * 256 + g_cand[o * CAP]);
        }
    }
    int tot = contr;
    unsigned fk = firstkey;
#pragma unroll
    for (int off = 1; off < 64; off <<= 1) {
        tot += __shfl_xor(tot, off);
        fk = min(fk, (unsigned)__shfl_xor((int)fk, off));
    }

    int k;
    if (tot <= 1) {                     // block-uniform branch
        k = (int)(fk & 0xffffu);
    } else {
        const float* zr = x + (size_t)row * D_DIM;
        const float sn = sn_arr[row];
        u64 best = ~0ull;
        for (int s = 0; s < NSPLIT; ++s) {
            if (dm[s] < thr) continue;
            const size_t o = (size_t)row * NSPLIT + s;
            const int c = g_cnt[o];
            if (c <= CAP) {
                if (t < c) {
                    const int kk = s * 256 + g_cand[o * CAP + t];
                    const float e = np_einsum_dot(zr, cb + (size_t)kk * D_DIM);
                    const float d = __fadd_rn(sn, __fmul_rn(-2.0f, e));
                    const u64 key = ((u64)fkey(d) << 32) | (unsigned)kk;
                    best = best < key ? best : key;
                }
            } else {                    // overflow backstop: all 256 codes
#pragma unroll
                for (int u = 0; u < 2; ++u) {
                    const int kk = s * 256 + t + u * 128;
                    const float e = np_einsum_dot(zr, cb + (size_t)kk * D_DIM);
                    const float d = __fadd_rn(sn, __fmul_rn(-2.0f, e));
                    const u64 key = ((u64)fkey(d) << 32) | (unsigned)kk;
                    best = best < key ? best : key;
                }
            }
        }
#pragma unroll
        for (int off = 1; off < 64; off <<= 1) {
            const u64 o2 = __shfl_xor(best, off);
            best = best < o2 ? best : o2;
        }
        if (lane == 0) s_red[wv] = best;
        __syncthreads();
        const u64 b2 = s_red[0] < s_red[1] ? s_red[0] : s_red[1];
        k = (int)(b2 & 0xffffffffu);
    }

    // gather + straight-through + loss partial
    const float4 c4 = ((const float4*)(cb + (size_t)k   * D_DIM))[t];
    const float4 xv = ((const float4*)(x  + (size_t)row * D_DIM))[t];
    float4 o;
    o.x = __fadd_rn(xv.x, __fsub_rn(c4.x, xv.x));
    o.y = __fadd_rn(xv.y, __fsub_rn(c4.y, xv.y));
    o.z = __fadd_rn(xv.z, __fsub_rn(c4.z, xv.z));
    o.w = __fadd_rn(xv.w, __fsub_rn(c4.w, xv.w));
    ((float4*)(zq + (size_t)row * D_DIM))[t] = o;
    const double d0 = (double)c4.x - (double)xv.x;
    const double d1 = (double)c4.y - (double)xv.y;
    const double d2 = (double)c4.z - (double)xv.z;
    const double d3 = (double)c4.w - (double)xv.w;
    double s = d0 * d0 + d1 * d1 + d2 * d2 + d3 * d3;
#pragma unroll
    for (int off = 32; off > 0; off >>= 1) s += __shfl_xor(s, off, 64);
    if (lane == 0) s_ls[wv] = s;
    __syncthreads();
    if (t == 0) {
        psum[row] = s_ls[0] + s_ls[1];
        idx_f[row] = (float)k;
        __threadfence();
        s_last = (atomicAdd(done, 1) == N_ROWS - 1);
    }
    __syncthreads();
    if (s_last) {                       // last block: reduce losses
        __threadfence();
        double s2 = 0.0;
        for (int i = t; i < N_ROWS; i += 128) s2 += psum[i];
#pragma unroll
        for (int off = 32; off > 0; off >>= 1) s2 += __shfl_xor(s2, off, 64);
        if (lane == 0) s_ls[wv] = s2;
        __syncthreads();
        if (t == 0) {
            const float l = (float)((s_ls[0] + s_ls[1]) / (double)((size_t)N_ROWS * D_DIM));
            losses[0] = l;
            losses[1] = l;
        }
    }
}

extern "C" void kernel_launch(void* const* d_in, const int* in_sizes, int n_in,
                              void* d_out, int out_size, void* d_ws, size_t ws_size,
                              hipStream_t stream) {
    const float* x  = (const float*)d_in[0];   // [16384, 512]
    const float* cb = (const float*)d_in[1];   // [8192, 512]
    float* out    = (float*)d_out;
    float* zq     = out;
    float* losses = out + (size_t)N_ROWS * D_DIM;
    float* idx_f  = losses + 2;
    char* ws = (char*)d_ws;

    const bool pre = (ws_size >= ((size_t)32 << 20));
    char* base = pre ? (ws + ((size_t)24 << 20)) : ws;

    float*  g_dmax = (float*)(base);                     // 2048 KB
    uchar*  g_cnt  = (uchar*)(base + (2048u << 10));     //  512 KB
    uchar*  g_cand = (uchar*)(base + (2560u << 10));     // 4096 KB
    float*  sn     = (float*)(base + (6656u << 10));     //   64 KB
    double* psum   = (double*)(base + (6720u << 10));    //  128 KB
    int*    done   = (int*)  (base + (6848u << 10));     //   64 KB slot

    if (pre) {
        ushort* xb  = (ushort*)ws;                               // 16 MB
        ushort* cbb = (ushort*)(ws + ((size_t)16 << 20));        // 8 MB
        hipLaunchKernelGGL(vq_prepass, dim3(8192), dim3(256), 0, stream,
                           x, cb, (unsigned*)xb, (unsigned*)cbb, sn, done);
        hipLaunchKernelGGL(vq_screen_pre, dim3(K_CODES / 256, N_ROWS / 128), dim3(256), 0, stream,
                           xb, cbb, g_dmax, g_cnt, g_cand);
    } else {
        hipLaunchKernelGGL(vq_sn, dim3(N_ROWS / 8), dim3(256), 0, stream,
                           x, sn, done);
        hipLaunchKernelGGL(vq_screen_np, dim3(K_CODES / 256, N_ROWS / 128), dim3(256), 0, stream,
                           x, cb, g_dmax, g_cnt, g_cand);
    }
    hipLaunchKernelGGL(vq_tail, dim3(N_ROWS), dim3(128), 0, stream,
                       x, cb, sn, g_dmax, g_cnt, g_cand, idx_f, zq, psum, done, losses);
}